// Round 1
// baseline (3576.534 us; speedup 1.0000x reference)
//
#include <hip/hip_runtime.h>
#include <hip/hip_bf16.h>

#define NN 50000
#define NE 200000
#define HEADS 4
#define EPSV 1e-5f
#define NEGS 0.01f

using f32x4 = __attribute__((ext_vector_type(4))) float;
using s16x8 = __attribute__((ext_vector_type(8))) short;
using bf16x8 = __attribute__((ext_vector_type(8))) __bf16;

__device__ __forceinline__ short f2bf(float f) {
    union { float f; unsigned u; } v; v.f = f;
    unsigned r = v.u + 0x7FFFu + ((v.u >> 16) & 1u);
    return (short)(r >> 16);
}
__device__ __forceinline__ float bf2f(short s) {
    union { unsigned u; float f; } v; v.u = ((unsigned)(unsigned short)s) << 16;
    return v.f;
}
__device__ __forceinline__ f32x4 mfma16(s16x8 a, s16x8 b, f32x4 c) {
    return __builtin_amdgcn_mfma_f32_16x16x32_bf16(
        __builtin_bit_cast(bf16x8, a), __builtin_bit_cast(bf16x8, b), c, 0, 0, 0);
}

// ---------------- weight prep: fp32 -> bf16, transposed to [col][k] ----------------
__global__ void prep_weights(const float* __restrict__ Kv2v, const float* __restrict__ Vv2v,
                             const float* __restrict__ inpW,
                             const float* __restrict__ Ke2v, const float* __restrict__ Ve2v,
                             const float* __restrict__ luW, const float* __restrict__ msgW,
                             const float* __restrict__ catW,
                             short* __restrict__ nodeW_t, short* __restrict__ KW_t,
                             short* __restrict__ VW_t, short* __restrict__ luW_t,
                             short* __restrict__ msgW_t, short* __restrict__ catW_t)
{
    int i = blockIdx.x * 256 + threadIdx.x;
    if (i < 147456) {                       // nodeW_t [1152][128]
        int j = i >> 7, k = i & 127;
        float v;
        if (j < 512)       v = Kv2v[(j >> 7) * 16384 + k * 128 + (j & 127)];
        else if (j < 1024) v = Vv2v[((j - 512) >> 7) * 16384 + k * 128 + (j & 127)];
        else               v = inpW[k * 128 + (j - 1024)];
        nodeW_t[i] = f2bf(v);
        return;
    }
    i -= 147456;
    if (i < 65536) { int h = i >> 14, rem = i & 16383, col = rem >> 7, k = rem & 127;
        KW_t[i] = f2bf(Ke2v[h * 16384 + k * 128 + col]); return; }
    i -= 65536;
    if (i < 65536) { int h = i >> 14, rem = i & 16383, col = rem >> 7, k = rem & 127;
        VW_t[i] = f2bf(Ve2v[h * 16384 + k * 128 + col]); return; }
    i -= 65536;
    if (i < 262144) { int h = i >> 16, rem = i & 65535, col = rem >> 8, k = rem & 255;
        luW_t[i] = f2bf(luW[h * 65536 + k * 256 + col]); return; }
    i -= 262144;
    if (i < 131072) { int h = i >> 15, rem = i & 32767, col = rem >> 8, k = rem & 255;
        msgW_t[i] = f2bf(msgW[h * 32768 + k * 128 + col]); return; }
    i -= 131072;
    if (i < 65536) { int h = i >> 14, rem = i & 16383, col = rem >> 7, k = rem & 127;
        catW_t[i] = f2bf(catW[(h * 128 + k) * 128 + col]); return; }
}

// ---------------- node projections: Kv/Vv (all heads) + residual, one GEMM ----------------
__global__ __launch_bounds__(256, 2)
void node_proj(const float* __restrict__ x, const short* __restrict__ nodeW_t,
               short* __restrict__ Kv_all, short* __restrict__ Vv_all,
               float* __restrict__ resid)
{
    __shared__ alignas(16) short xt[64 * 128];
    const int tid = threadIdx.x;
    const int row0 = blockIdx.x * 64;
    #pragma unroll
    for (int it = 0; it < 8; ++it) {
        int idx4 = it * 256 + tid;
        int r = idx4 >> 5;
        int c = (idx4 & 31) * 4;
        float4 v = {0.f, 0.f, 0.f, 0.f};
        if (row0 + r < NN) v = *(const float4*)(x + (size_t)(row0 + r) * 128 + c);
        short4 sw; sw.x = f2bf(v.x); sw.y = f2bf(v.y); sw.z = f2bf(v.z); sw.w = f2bf(v.w);
        int byte = (r * 256 + c * 2) ^ ((r & 7) << 4);
        *(short4*)((char*)xt + byte) = sw;
    }
    __syncthreads();
    const int lane = tid & 63, w = tid >> 6;
    const int l15 = lane & 15, lg = lane >> 4;
    const int rloc = w * 16 + l15;
    s16x8 a[4];
    #pragma unroll
    for (int ks = 0; ks < 4; ++ks) {
        int byte = (rloc * 256 + (ks * 32 + lg * 8) * 2) ^ ((rloc & 7) << 4);
        a[ks] = *(const s16x8*)((const char*)xt + byte);
    }
    const int rowC = row0 + w * 16 + lg * 4;
    for (int nt = 0; nt < 72; ++nt) {
        int j = nt * 16 + l15;
        f32x4 acc = (f32x4){0.f, 0.f, 0.f, 0.f};
        #pragma unroll
        for (int ks = 0; ks < 4; ++ks)
            acc = mfma16(a[ks], *(const s16x8*)(nodeW_t + j * 128 + ks * 32 + lg * 8), acc);
        #pragma unroll
        for (int r = 0; r < 4; ++r) {
            int row = rowC + r;
            if (row >= NN) continue;
            if (j < 512)       Kv_all[(size_t)row * 512 + j] = f2bf(acc[r]);
            else if (j < 1024) Vv_all[(size_t)row * 512 + (j - 512)] = f2bf(acc[r]);
            else               resid[(size_t)row * 128 + (j - 1024)] = acc[r];
        }
    }
}

// ---------------- fused edge pipeline ----------------
__global__ __launch_bounds__(256, 2)
void edge_kernel(const float* __restrict__ ef, const int* __restrict__ eidx,
                 const short* __restrict__ Kv_all, const short* __restrict__ Vv_all,
                 const short* __restrict__ KW_t, const short* __restrict__ VW_t,
                 const short* __restrict__ luW_t, const short* __restrict__ msgW_t,
                 const short* __restrict__ catW_t,
                 const float* __restrict__ lu_b, const float* __restrict__ ln1_g,
                 const float* __restrict__ ln1_b, const float* __restrict__ msg_b,
                 const float* __restrict__ ln2_g, const float* __restrict__ ln2_b,
                 float* __restrict__ out1)
{
    __shared__ alignas(16) short eft[64 * 128];       // 16 KB, bf16 edge_feature tile
    __shared__ alignas(16) short scratch[4][6144];    // 12 KB per wave: m1g@0 (8K), VE/m2@8192 (4K)
    const int tid = threadIdx.x;
    const int e0b = blockIdx.x * 64;

    #pragma unroll
    for (int it = 0; it < 8; ++it) {
        int idx4 = it * 256 + tid;
        int r = idx4 >> 5;
        int c = (idx4 & 31) * 4;
        const float4 v = *(const float4*)(ef + (size_t)(e0b + r) * 128 + c);
        short4 s4; s4.x = f2bf(v.x); s4.y = f2bf(v.y); s4.z = f2bf(v.z); s4.w = f2bf(v.w);
        int byte = (r * 256 + c * 2) ^ ((r & 7) << 4);
        *(short4*)((char*)eft + byte) = s4;
    }
    __syncthreads();

    const int lane = tid & 63, w = tid >> 6;
    const int l15 = lane & 15, lg = lane >> 4;
    const int e0 = e0b + w * 16;
    const int rb = lg * 4;
    const int rloc = w * 16 + l15;

    const int srcA = eidx[e0 + l15];
    int srcC[4], dstC[4];
    #pragma unroll
    for (int r = 0; r < 4; ++r) {
        srcC[r] = eidx[e0 + rb + r];
        dstC[r] = eidx[NE + e0 + rb + r];
    }
    char* myscr = (char*)scratch[w];
    const float scale = 0.0625f;   // 1/sqrt(2*OUT)

    f32x4 outc[8];
    #pragma unroll
    for (int nt = 0; nt < 8; ++nt) outc[nt] = (f32x4){0.f, 0.f, 0.f, 0.f};

    for (int h = 0; h < HEADS; ++h) {
        // ---- stage A: KE = ef@Ke2v, VE = ef@Ve2v ----
        f32x4 accK[8], accV[8];
        #pragma unroll
        for (int nt = 0; nt < 8; ++nt) { accK[nt] = (f32x4){0,0,0,0}; accV[nt] = (f32x4){0,0,0,0}; }
        #pragma unroll
        for (int ks = 0; ks < 4; ++ks) {
            int byte = (rloc * 256 + (ks * 32 + lg * 8) * 2) ^ ((rloc & 7) << 4);
            s16x8 a = *(const s16x8*)((const char*)eft + byte);
            #pragma unroll
            for (int nt = 0; nt < 8; ++nt) {
                const int wco = (h * 128 + nt * 16 + l15) * 128 + ks * 32 + lg * 8;
                accK[nt] = mfma16(a, *(const s16x8*)(KW_t + wco), accK[nt]);
                accV[nt] = mfma16(a, *(const s16x8*)(VW_t + wco), accV[nt]);
            }
        }
        #pragma unroll
        for (int nt = 0; nt < 8; ++nt) {        // VE -> scratch @8192 [16][128]
            int c = nt * 16 + l15;
            #pragma unroll
            for (int r = 0; r < 4; ++r) {
                int row = rb + r;
                int byte = 8192 + ((row * 256 + c * 2) ^ ((row & 7) << 4));
                *(short*)(myscr + byte) = f2bf(accV[nt][r]);
            }
        }
        __syncthreads();

        // ---- stage B: alpha = [q*k1, q*KE]*scale -> LN -> sigmoid gate ----
        float gatev[16][4];
        #pragma unroll
        for (int r = 0; r < 4; ++r) {
            const short* qp = Kv_all + (size_t)dstC[r] * 512 + h * 128 + l15;
            const short* kp = Kv_all + (size_t)srcC[r] * 512 + h * 128 + l15;
            float al[16];
            float s = 0.f, s2 = 0.f;
            #pragma unroll
            for (int nt = 0; nt < 8; ++nt) {
                float q  = bf2f(qp[nt * 16]);
                float k1 = bf2f(kp[nt * 16]);
                float alo = q * k1 * scale;
                float ahi = q * accK[nt][r] * scale;
                al[nt] = alo; al[nt + 8] = ahi;
                s += alo + ahi; s2 += alo * alo + ahi * ahi;
            }
            #pragma unroll
            for (int m = 1; m < 16; m <<= 1) { s += __shfl_xor(s, m); s2 += __shfl_xor(s2, m); }
            float mean = s * (1.f / 256.f);
            float var  = s2 * (1.f / 256.f) - mean * mean;
            float rstd = rsqrtf(var + EPSV);
            #pragma unroll
            for (int i = 0; i < 16; ++i) {
                int c = i * 16 + l15;   // column in [0,256)
                float z = (al[i] - mean) * rstd * ln1_g[h * 256 + c] + ln1_b[h * 256 + c];
                gatev[i][r] = 1.f / (1.f + __expf(-z));
            }
        }

        // ---- stage C: m1 = ([Vv_src|VE] @ luW + lu_b) * gate ----
        f32x4 m1[16];
        #pragma unroll
        for (int nt = 0; nt < 16; ++nt) m1[nt] = (f32x4){0,0,0,0};
        #pragma unroll
        for (int ks = 0; ks < 8; ++ks) {
            s16x8 a;
            if (ks < 4) {
                a = *(const s16x8*)(Vv_all + (size_t)srcA * 512 + h * 128 + ks * 32 + lg * 8);
            } else {
                int byte = 8192 + ((l15 * 256 + ((ks - 4) * 32 + lg * 8) * 2) ^ ((l15 & 7) << 4));
                a = *(const s16x8*)(myscr + byte);
            }
            #pragma unroll
            for (int nt = 0; nt < 16; ++nt) {
                const int wco = (h * 256 + nt * 16 + l15) * 256 + ks * 32 + lg * 8;
                m1[nt] = mfma16(a, *(const s16x8*)(luW_t + wco), m1[nt]);
            }
        }
        #pragma unroll
        for (int nt = 0; nt < 16; ++nt) {       // m1g bf16 -> scratch @0 [16][256]
            int c = nt * 16 + l15;
            float bias = lu_b[h * 256 + c];
            #pragma unroll
            for (int r = 0; r < 4; ++r) {
                int row = rb + r;
                int byte = (row * 512 + c * 2) ^ ((row & 7) << 4);
                *(short*)(myscr + byte) = f2bf((m1[nt][r] + bias) * gatev[nt][r]);
            }
        }
        __syncthreads();

        // ---- stage D: m2 = leaky(LN(m1g @ msgW + msg_b)*g2 + b2) ----
        f32x4 m2[8];
        #pragma unroll
        for (int nt = 0; nt < 8; ++nt) m2[nt] = (f32x4){0,0,0,0};
        #pragma unroll
        for (int ks = 0; ks < 8; ++ks) {
            int byte = (l15 * 512 + (ks * 32 + lg * 8) * 2) ^ ((l15 & 7) << 4);
            s16x8 a = *(const s16x8*)(myscr + byte);
            #pragma unroll
            for (int nt = 0; nt < 8; ++nt) {
                const int wco = (h * 128 + nt * 16 + l15) * 256 + ks * 32 + lg * 8;
                m2[nt] = mfma16(a, *(const s16x8*)(msgW_t + wco), m2[nt]);
            }
        }
        float s[4] = {0,0,0,0}, s2[4] = {0,0,0,0};
        #pragma unroll
        for (int nt = 0; nt < 8; ++nt) {
            int c = nt * 16 + l15;
            float bias = msg_b[h * 128 + c];
            #pragma unroll
            for (int r = 0; r < 4; ++r) {
                float v = m2[nt][r] + bias;
                m2[nt][r] = v;
                s[r] += v; s2[r] += v * v;
            }
        }
        #pragma unroll
        for (int m = 1; m < 16; m <<= 1) {
            #pragma unroll
            for (int r = 0; r < 4; ++r) { s[r] += __shfl_xor(s[r], m); s2[r] += __shfl_xor(s2[r], m); }
        }
        float mean[4], rstd[4];
        #pragma unroll
        for (int r = 0; r < 4; ++r) {
            mean[r] = s[r] * (1.f / 128.f);
            float var = s2[r] * (1.f / 128.f) - mean[r] * mean[r];
            rstd[r] = rsqrtf(var + EPSV);
        }
        #pragma unroll
        for (int nt = 0; nt < 8; ++nt) {        // m2 bf16 -> scratch @8192 [16][128]
            int c = nt * 16 + l15;
            float g2 = ln2_g[h * 128 + c], b2 = ln2_b[h * 128 + c];
            #pragma unroll
            for (int r = 0; r < 4; ++r) {
                float v = (m2[nt][r] - mean[r]) * rstd[r] * g2 + b2;
                v = v > 0.f ? v : v * NEGS;
                int row = rb + r;
                int byte = 8192 + ((row * 256 + c * 2) ^ ((row & 7) << 4));
                *(short*)(myscr + byte) = f2bf(v);
            }
        }
        __syncthreads();

        // ---- stage E: outc += m2 @ catW_h ----
        #pragma unroll
        for (int ks = 0; ks < 4; ++ks) {
            int byte = 8192 + ((l15 * 256 + (ks * 32 + lg * 8) * 2) ^ ((l15 & 7) << 4));
            s16x8 a = *(const s16x8*)(myscr + byte);
            #pragma unroll
            for (int nt = 0; nt < 8; ++nt) {
                const int wco = (h * 128 + nt * 16 + l15) * 128 + ks * 32 + lg * 8;
                outc[nt] = mfma16(a, *(const s16x8*)(catW_t + wco), outc[nt]);
            }
        }
        __syncthreads();   // protect m2 reads from next head's VE writes
    }

    // ---- scatter: one 128-wide atomic add per edge (all heads pre-projected) ----
    #pragma unroll
    for (int nt = 0; nt < 8; ++nt) {
        int c = nt * 16 + l15;
        #pragma unroll
        for (int r = 0; r < 4; ++r)
            atomicAdd(out1 + (size_t)dstC[r] * 128 + c, outc[nt][r]);
    }
}

// ---------------- BN statistics ----------------
__global__ void bn_stats(const float* __restrict__ out1, const float* __restrict__ cat_b,
                         float* __restrict__ stats)
{
    const int col = threadIdx.x;
    const int r0 = blockIdx.x * 128;
    const float cb = cat_b[col];
    float s = 0.f, s2 = 0.f;
    for (int i = 0; i < 128; ++i) {
        int row = r0 + i;
        if (row < NN) {
            float v = out1[(size_t)row * 128 + col] + cb;
            s += v; s2 += v * v;
        }
    }
    atomicAdd(stats + col, s);
    atomicAdd(stats + 128 + col, s2);
}

// ---------------- finalize: BN + leaky + residual ----------------
__global__ void finalize(const float* __restrict__ out1, const float* __restrict__ resid,
                         const float* __restrict__ stats, const float* __restrict__ cat_b,
                         const float* __restrict__ bn_g, const float* __restrict__ bn_b,
                         const float* __restrict__ inp_b, float* __restrict__ out)
{
    int i = blockIdx.x * 256 + threadIdx.x;
    if (i >= NN * 128) return;
    int col = i & 127;
    float mu = stats[col] * (1.f / NN);
    float var = stats[128 + col] * (1.f / NN) - mu * mu;
    float rstd = rsqrtf(var + EPSV);
    float v = out1[i] + cat_b[col];
    v = (v - mu) * rstd * bn_g[col] + bn_b[col];
    v = v > 0.f ? v : v * NEGS;
    out[i] = v + resid[i] + inp_b[col];
}

extern "C" void kernel_launch(void* const* d_in, const int* in_sizes, int n_in,
                              void* d_out, int out_size, void* d_ws, size_t ws_size,
                              hipStream_t stream)
{
    (void)in_sizes; (void)n_in; (void)out_size; (void)ws_size;
    const float* x     = (const float*)d_in[0];
    const int*   eidx  = (const int*)d_in[1];
    const float* ef    = (const float*)d_in[2];
    const float* Kv2v  = (const float*)d_in[3];
    const float* Ke2v  = (const float*)d_in[4];
    const float* Vv2v  = (const float*)d_in[5];
    const float* Ve2v  = (const float*)d_in[6];
    const float* lu_W  = (const float*)d_in[7];
    const float* lu_b  = (const float*)d_in[8];
    const float* ln1_g = (const float*)d_in[9];
    const float* ln1_b = (const float*)d_in[10];
    const float* msg_W = (const float*)d_in[11];
    const float* msg_b = (const float*)d_in[12];
    const float* ln2_g = (const float*)d_in[13];
    const float* ln2_b = (const float*)d_in[14];
    const float* cat_W = (const float*)d_in[15];
    const float* cat_b = (const float*)d_in[16];
    const float* inp_W = (const float*)d_in[17];
    const float* inp_b = (const float*)d_in[18];
    const float* bn_g  = (const float*)d_in[19];
    const float* bn_b  = (const float*)d_in[20];

    char* ws = (char*)d_ws;
    short* nodeW_t = (short*)(ws + 0);          // 294912
    short* KW_t    = (short*)(ws + 294912);     // 131072
    short* VW_t    = (short*)(ws + 425984);     // 131072
    short* luW_t   = (short*)(ws + 557056);     // 524288
    short* msgW_t  = (short*)(ws + 1081344);    // 262144
    short* catW_t  = (short*)(ws + 1343488);    // 131072
    short* Kv_all  = (short*)(ws + 1474560);    // 51,200,000
    short* Vv_all  = (short*)(ws + 52674560);   // 51,200,000
    float* resid   = (float*)(ws + 103874560);  // 25,600,000
    float* out1    = (float*)(ws + 129474560);  // 25,600,000
    float* stats   = (float*)(ws + 155074560);  // 1024

    hipMemsetAsync(out1, 0, 25600000 + 1024, stream);   // out1 + stats (contiguous)
    prep_weights<<<2880, 256, 0, stream>>>(Kv2v, Vv2v, inp_W, Ke2v, Ve2v, lu_W, msg_W, cat_W,
                                           nodeW_t, KW_t, VW_t, luW_t, msgW_t, catW_t);
    node_proj<<<782, 256, 0, stream>>>(x, nodeW_t, Kv_all, Vv_all, resid);
    edge_kernel<<<3125, 256, 0, stream>>>(ef, eidx, Kv_all, Vv_all, KW_t, VW_t, luW_t,
                                          msgW_t, catW_t, lu_b, ln1_g, ln1_b, msg_b,
                                          ln2_g, ln2_b, out1);
    bn_stats<<<391, 128, 0, stream>>>(out1, cat_b, stats);
    finalize<<<25000, 256, 0, stream>>>(out1, resid, stats, cat_b, bn_g, bn_b, inp_b,
                                        (float*)d_out);
}